// Round 3
// baseline (589.077 us; speedup 1.0000x reference)
//
#include <hip/hip_runtime.h>
#include <hip/hip_bf16.h>
#include <math.h>

#define N_NODES 50000
#define N_EDGES 800000
#define D 64
#define ED 32

// ws layout (float element offsets)
#define Q_OFF    0          // 3,200,000
#define K_OFF    3200000    // 3,200,000
#define V_OFF    6400000    // 3,200,000
#define OS_OFF   9600000    // out_sum: 3,200,000
#define CNT_OFF  12800000   // 50,000
#define S_OFF    12850000   // 8 (+8 pad)
#define H_OFF    12850016   // 3,200,000
#define F1_OFF   16050016   // 6,400,000
// CSR scratch aliases h / f1 (dead until k_ln1 / k_ffn1):
#define DEG_OFF  H_OFF              // 50,000 ints
#define RP_OFF   (H_OFF + 50000)    // 50,001 ints
#define WOFF_OFF (H_OFF + 100002)   // 50,000 ints
#define PE_OFF   F1_OFF             // 800,000 int2 (8B-aligned: offset even)

// ---------------- node QKV projection: thread per node, W in LDS ----------------
__global__ __launch_bounds__(256) void k_qkv(
    const float* __restrict__ x,
    const float* __restrict__ Wq, const float* __restrict__ bq,
    const float* __restrict__ Wk, const float* __restrict__ bk,
    const float* __restrict__ Wv, const float* __restrict__ bv,
    float* __restrict__ q, float* __restrict__ k, float* __restrict__ v) {
  __shared__ float Wl[64 * 64];
  const float* W; const float* b; float* o;
  if (blockIdx.y == 0)      { W = Wq; b = bq; o = q; }
  else if (blockIdx.y == 1) { W = Wk; b = bk; o = k; }
  else                      { W = Wv; b = bv; o = v; }
  for (int t = threadIdx.x; t < 4096; t += 256) Wl[t] = W[t];
  __syncthreads();
  const int n = blockIdx.x * 256 + threadIdx.x;
  if (n >= N_NODES) return;

  float4 acc[16];
#pragma unroll
  for (int j4 = 0; j4 < 16; ++j4) acc[j4] = make_float4(0.f, 0.f, 0.f, 0.f);
  const float4* xr = reinterpret_cast<const float4*>(x + (size_t)n * 64);
#pragma unroll 2
  for (int i4 = 0; i4 < 16; ++i4) {
    float4 xv = xr[i4];
#pragma unroll
    for (int s = 0; s < 4; ++s) {
      const float xi = (s == 0) ? xv.x : (s == 1) ? xv.y : (s == 2) ? xv.z : xv.w;
      const float4* wrow = reinterpret_cast<const float4*>(Wl + (i4 * 4 + s) * 64);
#pragma unroll
      for (int j4 = 0; j4 < 16; ++j4) {
        float4 wv = wrow[j4];
        acc[j4].x = fmaf(xi, wv.x, acc[j4].x);
        acc[j4].y = fmaf(xi, wv.y, acc[j4].y);
        acc[j4].z = fmaf(xi, wv.z, acc[j4].z);
        acc[j4].w = fmaf(xi, wv.w, acc[j4].w);
      }
    }
  }
  const float4* b4 = reinterpret_cast<const float4*>(b);
  float4* orow = reinterpret_cast<float4*>(o + (size_t)n * 64);
#pragma unroll
  for (int j4 = 0; j4 < 16; ++j4) {
    float4 a = acc[j4]; float4 bb = b4[j4];
    a.x += bb.x; a.y += bb.y; a.z += bb.z; a.w += bb.w;
    orow[j4] = a;
  }
}

// ---------------- CSR build: histogram ----------------
__global__ __launch_bounds__(256) void k_hist(const int* __restrict__ edst,
                                              int* __restrict__ deg) {
  const int i = blockIdx.x * 256 + threadIdx.x;
  if (i < N_EDGES) atomicAdd(&deg[edst[i]], 1);
}

// ---------------- CSR build: single-block exclusive scan over 50k ----------------
__global__ __launch_bounds__(1024) void k_scan(const int* __restrict__ deg,
                                               int* __restrict__ rowptr,
                                               int* __restrict__ woff) {
  __shared__ int lsum[1024];
  const int tid = threadIdx.x;
  const int CH = 49;  // 1024*49 = 50176 >= 50000
  const int base = tid * CH;
  int s = 0;
  for (int i = 0; i < CH; ++i) {
    const int idx = base + i;
    if (idx < N_NODES) s += deg[idx];
  }
  lsum[tid] = s;
  __syncthreads();
  for (int off = 1; off < 1024; off <<= 1) {
    const int t = (tid >= off) ? lsum[tid - off] : 0;
    __syncthreads();
    lsum[tid] += t;
    __syncthreads();
  }
  int ex = (tid == 0) ? 0 : lsum[tid - 1];
  for (int i = 0; i < CH; ++i) {
    const int idx = base + i;
    if (idx < N_NODES) {
      rowptr[idx] = ex;
      woff[idx] = ex;
      ex += deg[idx];
    }
  }
  if (tid == 1023) rowptr[N_NODES] = ex;  // 800000
}

// ---------------- CSR build: scatter (src, eid) by dst ----------------
__global__ __launch_bounds__(256) void k_scatter(const int* __restrict__ esrc,
                                                 const int* __restrict__ edst,
                                                 int* __restrict__ woff,
                                                 int2* __restrict__ pe) {
  const int i = blockIdx.x * 256 + threadIdx.x;
  if (i < N_EDGES) {
    const int d = edst[i];
    const int pos = atomicAdd(&woff[d], 1);
    pe[pos] = make_int2(esrc[i], i);
  }
}

// ---------------- gather: wave per node, register accumulation, no atomics ----------------
__global__ __launch_bounds__(256) void k_gather(
    const int* __restrict__ rowptr, const int2* __restrict__ pe,
    const float* __restrict__ ea, const float* __restrict__ q,
    const float* __restrict__ k, const float* __restrict__ v,
    const float* __restrict__ We, const float* __restrict__ be,
    float* __restrict__ osum, float* __restrict__ cnt, float* __restrict__ S) {
  const int lane = threadIdx.x & 63;
  const int wid  = threadIdx.x >> 6;
  float wec[32];
#pragma unroll
  for (int i = 0; i < 32; ++i) wec[i] = We[i * 64 + lane];
  const float bel = be[lane];
  float sacc = 0.f;
  const int nw = gridDim.x * 4;
  for (int n = blockIdx.x * 4 + wid; n < N_NODES; n += nw) {
    const int beg = rowptr[n];
    const int end = rowptr[n + 1];
    const float qj = q[(size_t)n * 64 + lane];
    // self-loop: src=dst=n, ea=0 -> ee=be
    float kj = k[(size_t)n * 64 + lane];
    float vj = v[(size_t)n * 64 + lane];
    float p = qj * (kj + bel);
    p += __shfl_xor(p, 1);
    p += __shfl_xor(p, 2);
    p += __shfl_xor(p, 4);
    float wv = __expf(p * 0.3535533905932738f);
    if ((lane & 7) == 0) sacc += wv;
    float macc = wv * (vj + bel);
    for (int j = beg; j < end; ++j) {
      const int2 pr = pe[j];
      const int src = __builtin_amdgcn_readfirstlane(pr.x);
      const int eid = __builtin_amdgcn_readfirstlane(pr.y);
      const float4* ear = reinterpret_cast<const float4*>(ea + (size_t)eid * 32);
      float eej = bel;
#pragma unroll
      for (int i4 = 0; i4 < 8; ++i4) {
        const float4 t = ear[i4];
        eej = fmaf(t.x, wec[i4 * 4 + 0], eej);
        eej = fmaf(t.y, wec[i4 * 4 + 1], eej);
        eej = fmaf(t.z, wec[i4 * 4 + 2], eej);
        eej = fmaf(t.w, wec[i4 * 4 + 3], eej);
      }
      kj = k[(size_t)src * 64 + lane];
      vj = v[(size_t)src * 64 + lane];
      p = qj * (kj + eej);
      p += __shfl_xor(p, 1);
      p += __shfl_xor(p, 2);
      p += __shfl_xor(p, 4);
      wv = __expf(p * 0.3535533905932738f);
      if ((lane & 7) == 0) sacc += wv;
      macc = fmaf(wv, vj + eej, macc);
    }
    osum[(size_t)n * 64 + lane] = macc;
    if (lane == 0) cnt[n] = (float)(end - beg + 1);
  }
  if ((lane & 7) == 0) atomicAdd(&S[lane >> 3], sacc);
}

// ---------------- epilogue 1: out/(S*cnt) @ Wo + bo, +x, LN1 -> h ----------------
__global__ __launch_bounds__(256) void k_ln1(
    const float* __restrict__ osum, const float* __restrict__ cnt,
    const float* __restrict__ S, const float* __restrict__ x,
    const float* __restrict__ Wo, const float* __restrict__ bo,
    const float* __restrict__ g1, const float* __restrict__ b1,
    float* __restrict__ h) {
  __shared__ float Wl[64 * 64];
  for (int t = threadIdx.x; t < 4096; t += 256) Wl[t] = Wo[t];
  __syncthreads();
  const int n = blockIdx.x * 256 + threadIdx.x;
  if (n >= N_NODES) return;

  float inv[8];
#pragma unroll
  for (int hh = 0; hh < 8; ++hh) inv[hh] = 1.0f / S[hh];
  const float invc = 1.0f / cnt[n];

  float val[64];
  const float4* osr = reinterpret_cast<const float4*>(osum + (size_t)n * 64);
#pragma unroll
  for (int j4 = 0; j4 < 16; ++j4) {
    float4 t = osr[j4];
    val[j4 * 4 + 0] = t.x * inv[(j4 * 4 + 0) >> 3] * invc;
    val[j4 * 4 + 1] = t.y * inv[(j4 * 4 + 1) >> 3] * invc;
    val[j4 * 4 + 2] = t.z * inv[(j4 * 4 + 2) >> 3] * invc;
    val[j4 * 4 + 3] = t.w * inv[(j4 * 4 + 3) >> 3] * invc;
  }

  float4 acc[16];
#pragma unroll
  for (int j4 = 0; j4 < 16; ++j4) acc[j4] = make_float4(0.f, 0.f, 0.f, 0.f);
#pragma unroll 4
  for (int i = 0; i < 64; ++i) {
    const float xi = val[i];
    const float4* wrow = reinterpret_cast<const float4*>(Wl + i * 64);
#pragma unroll
    for (int j4 = 0; j4 < 16; ++j4) {
      float4 wv = wrow[j4];
      acc[j4].x = fmaf(xi, wv.x, acc[j4].x);
      acc[j4].y = fmaf(xi, wv.y, acc[j4].y);
      acc[j4].z = fmaf(xi, wv.z, acc[j4].z);
      acc[j4].w = fmaf(xi, wv.w, acc[j4].w);
    }
  }

  const float4* xr = reinterpret_cast<const float4*>(x + (size_t)n * 64);
  const float4* bo4 = reinterpret_cast<const float4*>(bo);
  float t[64];
  float m = 0.f;
#pragma unroll
  for (int j4 = 0; j4 < 16; ++j4) {
    float4 xv = xr[j4]; float4 bb = bo4[j4];
    t[j4 * 4 + 0] = xv.x + acc[j4].x + bb.x;
    t[j4 * 4 + 1] = xv.y + acc[j4].y + bb.y;
    t[j4 * 4 + 2] = xv.z + acc[j4].z + bb.z;
    t[j4 * 4 + 3] = xv.w + acc[j4].w + bb.w;
    m += t[j4 * 4 + 0] + t[j4 * 4 + 1] + t[j4 * 4 + 2] + t[j4 * 4 + 3];
  }
  m *= (1.0f / 64.0f);
  float var = 0.f;
#pragma unroll
  for (int j = 0; j < 64; ++j) { const float dt = t[j] - m; var = fmaf(dt, dt, var); }
  var *= (1.0f / 64.0f);
  const float r = rsqrtf(var + 1e-5f);
  const float4* g14 = reinterpret_cast<const float4*>(g1);
  const float4* b14 = reinterpret_cast<const float4*>(b1);
  float4* hr = reinterpret_cast<float4*>(h + (size_t)n * 64);
#pragma unroll
  for (int j4 = 0; j4 < 16; ++j4) {
    float4 g = g14[j4]; float4 bb = b14[j4]; float4 o;
    o.x = (t[j4 * 4 + 0] - m) * r * g.x + bb.x;
    o.y = (t[j4 * 4 + 1] - m) * r * g.y + bb.y;
    o.z = (t[j4 * 4 + 2] - m) * r * g.z + bb.z;
    o.w = (t[j4 * 4 + 3] - m) * r * g.w + bb.w;
    hr[j4] = o;
  }
}

// ---------------- FFN stage 1: f1 = gelu(h @ Wf1 + bf1) ----------------
__global__ __launch_bounds__(256) void k_ffn1(
    const float* __restrict__ h, const float* __restrict__ Wf1,
    const float* __restrict__ bf1, float* __restrict__ f1) {
  __shared__ float Wl[64 * 128];
  for (int t = threadIdx.x; t < 8192; t += 256) Wl[t] = Wf1[t];
  __syncthreads();
  const int n = blockIdx.x * 256 + threadIdx.x;
  if (n >= N_NODES) return;

  float4 acc[32];
#pragma unroll
  for (int j4 = 0; j4 < 32; ++j4) acc[j4] = make_float4(0.f, 0.f, 0.f, 0.f);
  const float4* xr = reinterpret_cast<const float4*>(h + (size_t)n * 64);
#pragma unroll 2
  for (int i4 = 0; i4 < 16; ++i4) {
    float4 xv = xr[i4];
#pragma unroll
    for (int s = 0; s < 4; ++s) {
      const float xi = (s == 0) ? xv.x : (s == 1) ? xv.y : (s == 2) ? xv.z : xv.w;
      const float4* wrow = reinterpret_cast<const float4*>(Wl + (i4 * 4 + s) * 128);
#pragma unroll
      for (int j4 = 0; j4 < 32; ++j4) {
        float4 wv = wrow[j4];
        acc[j4].x = fmaf(xi, wv.x, acc[j4].x);
        acc[j4].y = fmaf(xi, wv.y, acc[j4].y);
        acc[j4].z = fmaf(xi, wv.z, acc[j4].z);
        acc[j4].w = fmaf(xi, wv.w, acc[j4].w);
      }
    }
  }
  const float4* b4 = reinterpret_cast<const float4*>(bf1);
  float4* orow = reinterpret_cast<float4*>(f1 + (size_t)n * 128);
#pragma unroll
  for (int j4 = 0; j4 < 32; ++j4) {
    float4 a = acc[j4]; float4 bb = b4[j4];
    a.x += bb.x; a.y += bb.y; a.z += bb.z; a.w += bb.w;
    a.x = 0.5f * a.x * (1.0f + erff(a.x * 0.7071067811865475f));
    a.y = 0.5f * a.y * (1.0f + erff(a.y * 0.7071067811865475f));
    a.z = 0.5f * a.z * (1.0f + erff(a.z * 0.7071067811865475f));
    a.w = 0.5f * a.w * (1.0f + erff(a.w * 0.7071067811865475f));
    orow[j4] = a;
  }
}

// ---------------- FFN stage 2 + residual + LN2 -> d_out ----------------
__global__ __launch_bounds__(256) void k_ffn2(
    const float* __restrict__ f1, const float* __restrict__ h,
    const float* __restrict__ Wf2, const float* __restrict__ bf2,
    const float* __restrict__ g2, const float* __restrict__ b2,
    float* __restrict__ out) {
  __shared__ float Wl[128 * 64];
  for (int t = threadIdx.x; t < 8192; t += 256) Wl[t] = Wf2[t];
  __syncthreads();
  const int n = blockIdx.x * 256 + threadIdx.x;
  if (n >= N_NODES) return;

  float4 acc[16];
#pragma unroll
  for (int j4 = 0; j4 < 16; ++j4) acc[j4] = make_float4(0.f, 0.f, 0.f, 0.f);
  const float4* fr = reinterpret_cast<const float4*>(f1 + (size_t)n * 128);
#pragma unroll 2
  for (int i4 = 0; i4 < 32; ++i4) {
    float4 fv = fr[i4];
#pragma unroll
    for (int s = 0; s < 4; ++s) {
      const float fi = (s == 0) ? fv.x : (s == 1) ? fv.y : (s == 2) ? fv.z : fv.w;
      const float4* wrow = reinterpret_cast<const float4*>(Wl + (i4 * 4 + s) * 64);
#pragma unroll
      for (int j4 = 0; j4 < 16; ++j4) {
        float4 wv = wrow[j4];
        acc[j4].x = fmaf(fi, wv.x, acc[j4].x);
        acc[j4].y = fmaf(fi, wv.y, acc[j4].y);
        acc[j4].z = fmaf(fi, wv.z, acc[j4].z);
        acc[j4].w = fmaf(fi, wv.w, acc[j4].w);
      }
    }
  }

  const float4* hr = reinterpret_cast<const float4*>(h + (size_t)n * 64);
  const float4* b4 = reinterpret_cast<const float4*>(bf2);
  float t[64];
  float m = 0.f;
#pragma unroll
  for (int j4 = 0; j4 < 16; ++j4) {
    float4 hv = hr[j4]; float4 bb = b4[j4];
    t[j4 * 4 + 0] = hv.x + acc[j4].x + bb.x;
    t[j4 * 4 + 1] = hv.y + acc[j4].y + bb.y;
    t[j4 * 4 + 2] = hv.z + acc[j4].z + bb.z;
    t[j4 * 4 + 3] = hv.w + acc[j4].w + bb.w;
    m += t[j4 * 4 + 0] + t[j4 * 4 + 1] + t[j4 * 4 + 2] + t[j4 * 4 + 3];
  }
  m *= (1.0f / 64.0f);
  float var = 0.f;
#pragma unroll
  for (int j = 0; j < 64; ++j) { const float dt = t[j] - m; var = fmaf(dt, dt, var); }
  var *= (1.0f / 64.0f);
  const float r = rsqrtf(var + 1e-5f);
  const float4* g24 = reinterpret_cast<const float4*>(g2);
  const float4* b24 = reinterpret_cast<const float4*>(b2);
  float4* orow = reinterpret_cast<float4*>(out + (size_t)n * 64);
#pragma unroll
  for (int j4 = 0; j4 < 16; ++j4) {
    float4 g = g24[j4]; float4 bb = b24[j4]; float4 o;
    o.x = (t[j4 * 4 + 0] - m) * r * g.x + bb.x;
    o.y = (t[j4 * 4 + 1] - m) * r * g.y + bb.y;
    o.z = (t[j4 * 4 + 2] - m) * r * g.z + bb.z;
    o.w = (t[j4 * 4 + 3] - m) * r * g.w + bb.w;
    orow[j4] = o;
  }
}

extern "C" void kernel_launch(void* const* d_in, const int* in_sizes, int n_in,
                              void* d_out, int out_size, void* d_ws, size_t ws_size,
                              hipStream_t stream) {
  const float* x    = (const float*)d_in[0];
  const int*   ei   = (const int*)d_in[1];
  const int*   esrc = ei;
  const int*   edst = ei + N_EDGES;
  const float* ea   = (const float*)d_in[2];
  const float* Wq   = (const float*)d_in[3];
  const float* bq   = (const float*)d_in[4];
  const float* Wk   = (const float*)d_in[5];
  const float* bk   = (const float*)d_in[6];
  const float* Wv   = (const float*)d_in[7];
  const float* bv   = (const float*)d_in[8];
  const float* We   = (const float*)d_in[9];
  const float* be   = (const float*)d_in[10];
  const float* Wo   = (const float*)d_in[11];
  const float* bo   = (const float*)d_in[12];
  const float* g1   = (const float*)d_in[13];
  const float* b1   = (const float*)d_in[14];
  const float* g2   = (const float*)d_in[15];
  const float* b2   = (const float*)d_in[16];
  const float* Wf1  = (const float*)d_in[17];
  const float* bf1  = (const float*)d_in[18];
  const float* Wf2  = (const float*)d_in[19];
  const float* bf2  = (const float*)d_in[20];

  float* ws   = (float*)d_ws;
  float* q    = ws + Q_OFF;
  float* k    = ws + K_OFF;
  float* v    = ws + V_OFF;
  float* osum = ws + OS_OFF;
  float* cnt  = ws + CNT_OFF;
  float* S    = ws + S_OFF;
  float* h    = ws + H_OFF;
  float* f1   = ws + F1_OFF;
  int*   deg    = (int*)(ws + DEG_OFF);
  int*   rowptr = (int*)(ws + RP_OFF);
  int*   woff   = (int*)(ws + WOFF_OFF);
  int2*  pe     = (int2*)(ws + PE_OFF);
  float* out  = (float*)d_out;

  // zero the histogram and the softmax denominator accumulator
  hipMemsetAsync(deg, 0, (size_t)N_NODES * sizeof(int), stream);
  hipMemsetAsync(S, 0, 16 * sizeof(float), stream);

  const dim3 B(256);
  const int nodeBlocks = (N_NODES + 255) / 256;  // 196
  const int edgeBlocks = (N_EDGES + 255) / 256;  // 3125

  k_qkv<<<dim3(nodeBlocks, 3), B, 0, stream>>>(x, Wq, bq, Wk, bk, Wv, bv, q, k, v);
  k_hist<<<dim3(edgeBlocks), B, 0, stream>>>(edst, deg);
  k_scan<<<dim3(1), dim3(1024), 0, stream>>>(deg, rowptr, woff);
  k_scatter<<<dim3(edgeBlocks), B, 0, stream>>>(esrc, edst, woff, pe);
  k_gather<<<dim3(2048), B, 0, stream>>>(rowptr, pe, ea, q, k, v, We, be, osum, cnt, S);
  k_ln1<<<dim3(nodeBlocks), B, 0, stream>>>(osum, cnt, S, x, Wo, bo, g1, b1, h);
  k_ffn1<<<dim3(nodeBlocks), B, 0, stream>>>(h, Wf1, bf1, f1);
  k_ffn2<<<dim3(nodeBlocks), B, 0, stream>>>(f1, h, Wf2, bf2, g2, b2, out);
}

// Round 4
// 530.513 us; speedup vs baseline: 1.1104x; 1.1104x over previous
//
#include <hip/hip_runtime.h>
#include <hip/hip_bf16.h>
#include <math.h>

#define N_NODES 50000
#define N_EDGES 800000
#define D 64
#define ED 32

// ws layout (float element offsets)
#define Q_OFF    0          // 3,200,000
#define K_OFF    3200000    // 3,200,000
#define V_OFF    6400000    // 3,200,000
#define OS_OFF   9600000    // out_sum: 3,200,000
#define CNT_OFF  12800000   // 50,000
#define S_OFF    12850000   // 8 (+8 pad)
#define H_OFF    12850016   // 3,200,000
#define F1_OFF   16050016   // 6,400,000
// CSR scratch aliases h / f1 (dead until k_ln1 / k_ffn1):
#define DEG_OFF  H_OFF              // 50,000 ints
#define RP_OFF   (H_OFF + 50000)    // 50,001 ints
#define WOFF_OFF (H_OFF + 100002)   // 50,000 ints
#define BSUM_OFF (H_OFF + 150002)   // 256 ints
#define PE_OFF   F1_OFF             // 800,000 int2 (8B-aligned)

// ---------------- node QKV projection: thread per node, W in LDS ----------------
__global__ __launch_bounds__(256) void k_qkv(
    const float* __restrict__ x,
    const float* __restrict__ Wq, const float* __restrict__ bq,
    const float* __restrict__ Wk, const float* __restrict__ bk,
    const float* __restrict__ Wv, const float* __restrict__ bv,
    float* __restrict__ q, float* __restrict__ k, float* __restrict__ v) {
  __shared__ float Wl[64 * 64];
  const float* W; const float* b; float* o;
  if (blockIdx.y == 0)      { W = Wq; b = bq; o = q; }
  else if (blockIdx.y == 1) { W = Wk; b = bk; o = k; }
  else                      { W = Wv; b = bv; o = v; }
  for (int t = threadIdx.x; t < 4096; t += 256) Wl[t] = W[t];
  __syncthreads();
  const int n = blockIdx.x * 256 + threadIdx.x;
  if (n >= N_NODES) return;

  float4 acc[16];
#pragma unroll
  for (int j4 = 0; j4 < 16; ++j4) acc[j4] = make_float4(0.f, 0.f, 0.f, 0.f);
  const float4* xr = reinterpret_cast<const float4*>(x + (size_t)n * 64);
#pragma unroll 2
  for (int i4 = 0; i4 < 16; ++i4) {
    float4 xv = xr[i4];
#pragma unroll
    for (int s = 0; s < 4; ++s) {
      const float xi = (s == 0) ? xv.x : (s == 1) ? xv.y : (s == 2) ? xv.z : xv.w;
      const float4* wrow = reinterpret_cast<const float4*>(Wl + (i4 * 4 + s) * 64);
#pragma unroll
      for (int j4 = 0; j4 < 16; ++j4) {
        float4 wv = wrow[j4];
        acc[j4].x = fmaf(xi, wv.x, acc[j4].x);
        acc[j4].y = fmaf(xi, wv.y, acc[j4].y);
        acc[j4].z = fmaf(xi, wv.z, acc[j4].z);
        acc[j4].w = fmaf(xi, wv.w, acc[j4].w);
      }
    }
  }
  const float4* b4 = reinterpret_cast<const float4*>(b);
  float4* orow = reinterpret_cast<float4*>(o + (size_t)n * 64);
#pragma unroll
  for (int j4 = 0; j4 < 16; ++j4) {
    float4 a = acc[j4]; float4 bb = b4[j4];
    a.x += bb.x; a.y += bb.y; a.z += bb.z; a.w += bb.w;
    orow[j4] = a;
  }
}

// ---------------- CSR build: histogram ----------------
__global__ __launch_bounds__(256) void k_hist(const int* __restrict__ edst,
                                              int* __restrict__ deg) {
  const int i = blockIdx.x * 256 + threadIdx.x;
  if (i < N_EDGES) atomicAdd(&deg[edst[i]], 1);
}

// ---------------- CSR build: 3-stage multi-block scan ----------------
__global__ __launch_bounds__(256) void k_scan_a(const int* __restrict__ deg,
                                                int* __restrict__ bsum) {
  __shared__ int lds[256];
  const int i = blockIdx.x * 256 + threadIdx.x;
  lds[threadIdx.x] = (i < N_NODES) ? deg[i] : 0;
  __syncthreads();
  for (int s = 128; s > 0; s >>= 1) {
    if (threadIdx.x < s) lds[threadIdx.x] += lds[threadIdx.x + s];
    __syncthreads();
  }
  if (threadIdx.x == 0) bsum[blockIdx.x] = lds[0];
}

__global__ __launch_bounds__(256) void k_scan_b(int* __restrict__ bsum, int nb) {
  __shared__ int lds[256];
  const int t = threadIdx.x;
  const int d = (t < nb) ? bsum[t] : 0;
  lds[t] = d;
  __syncthreads();
  for (int off = 1; off < 256; off <<= 1) {
    const int val = (t >= off) ? lds[t - off] : 0;
    __syncthreads();
    lds[t] += val;
    __syncthreads();
  }
  if (t < nb) bsum[t] = lds[t] - d;  // exclusive
}

__global__ __launch_bounds__(256) void k_scan_c(const int* __restrict__ deg,
                                                const int* __restrict__ bsum,
                                                int* __restrict__ rowptr,
                                                int* __restrict__ woff) {
  __shared__ int lds[256];
  const int i = blockIdx.x * 256 + threadIdx.x;
  const int d = (i < N_NODES) ? deg[i] : 0;
  lds[threadIdx.x] = d;
  __syncthreads();
  for (int off = 1; off < 256; off <<= 1) {
    const int val = (threadIdx.x >= off) ? lds[threadIdx.x - off] : 0;
    __syncthreads();
    lds[threadIdx.x] += val;
    __syncthreads();
  }
  const int ex = bsum[blockIdx.x] + lds[threadIdx.x] - d;
  if (i < N_NODES) { rowptr[i] = ex; woff[i] = ex; }
  if (i == N_NODES - 1) rowptr[N_NODES] = ex + d;
}

// ---------------- CSR build: scatter (src, eid) by dst ----------------
__global__ __launch_bounds__(256) void k_scatter(const int* __restrict__ esrc,
                                                 const int* __restrict__ edst,
                                                 int* __restrict__ woff,
                                                 int2* __restrict__ pe) {
  const int i = blockIdx.x * 256 + threadIdx.x;
  if (i < N_EDGES) {
    const int d = edst[i];
    const int pos = atomicAdd(&woff[d], 1);
    pe[pos] = make_int2(esrc[i], i);
  }
}

// ---------------- gather: wave per node, pipelined, no atomics ----------------
__global__ __launch_bounds__(256) void k_gather(
    const int* __restrict__ rowptr, const int2* __restrict__ pe,
    const float* __restrict__ ea, const float* __restrict__ q,
    const float* __restrict__ k, const float* __restrict__ v,
    const float* __restrict__ We, const float* __restrict__ be,
    float* __restrict__ osum, float* __restrict__ cnt, float* __restrict__ S) {
  const int lane = threadIdx.x & 63;
  const int wid  = threadIdx.x >> 6;
  float wec[32];
#pragma unroll
  for (int i = 0; i < 32; ++i) wec[i] = We[i * 64 + lane];
  const float bel = be[lane];
  float sacc = 0.f;
  const int nw = gridDim.x * 4;
  for (int n = blockIdx.x * 4 + wid; n < N_NODES; n += nw) {
    const int beg = rowptr[n];
    const int end = rowptr[n + 1];
    const float qj = q[(size_t)n * 64 + lane];
    // self-loop: src=dst=n, ea=0 -> ee=be
    {
      const float kj = k[(size_t)n * 64 + lane];
      const float vj = v[(size_t)n * 64 + lane];
      float p = qj * (kj + bel);
      p += __shfl_xor(p, 1);
      p += __shfl_xor(p, 2);
      p += __shfl_xor(p, 4);
      const float wv = __expf(p * 0.3535533905932738f);
      sacc += wv;  // uniform within 8-lane head group; flushed by group leader
      float macc = wv * (vj + bel);

      for (int jb = beg; jb < end; jb += 64) {
        const int m = (end - jb < 64) ? (end - jb) : 64;
        int2 prl = make_int2(0, 0);
        if (jb + lane < end) prl = pe[jb + lane];  // one coalesced load = 64 edges
        // preload edge 0
        int src = __shfl(prl.x, 0);
        int eid = __shfl(prl.y, 0);
        const float4* er = reinterpret_cast<const float4*>(ea + (size_t)eid * 32);
        float4 c0 = er[0], c1 = er[1], c2 = er[2], c3 = er[3];
        float4 c4 = er[4], c5 = er[5], c6 = er[6], c7 = er[7];
        float kc = k[(size_t)src * 64 + lane];
        float vc = v[(size_t)src * 64 + lane];
        for (int t = 0; t < m; ++t) {
          // issue next edge's loads first (hide latency under current compute)
          float4 p0 = c0, p1 = c1, p2 = c2, p3 = c3, p4 = c4, p5 = c5, p6 = c6, p7 = c7;
          float kn = kc, vn = vc;
          if (t + 1 < m) {
            const int s2 = __shfl(prl.x, t + 1);
            const int e2 = __shfl(prl.y, t + 1);
            const float4* er2 = reinterpret_cast<const float4*>(ea + (size_t)e2 * 32);
            p0 = er2[0]; p1 = er2[1]; p2 = er2[2]; p3 = er2[3];
            p4 = er2[4]; p5 = er2[5]; p6 = er2[6]; p7 = er2[7];
            kn = k[(size_t)s2 * 64 + lane];
            vn = v[(size_t)s2 * 64 + lane];
          }
          // eej = be + ea . We[:,lane], two accumulators for ILP
          float ee0 = bel, ee1 = 0.f;
          ee0 = fmaf(c0.x, wec[0],  ee0); ee1 = fmaf(c0.y, wec[1],  ee1);
          ee0 = fmaf(c0.z, wec[2],  ee0); ee1 = fmaf(c0.w, wec[3],  ee1);
          ee0 = fmaf(c1.x, wec[4],  ee0); ee1 = fmaf(c1.y, wec[5],  ee1);
          ee0 = fmaf(c1.z, wec[6],  ee0); ee1 = fmaf(c1.w, wec[7],  ee1);
          ee0 = fmaf(c2.x, wec[8],  ee0); ee1 = fmaf(c2.y, wec[9],  ee1);
          ee0 = fmaf(c2.z, wec[10], ee0); ee1 = fmaf(c2.w, wec[11], ee1);
          ee0 = fmaf(c3.x, wec[12], ee0); ee1 = fmaf(c3.y, wec[13], ee1);
          ee0 = fmaf(c3.z, wec[14], ee0); ee1 = fmaf(c3.w, wec[15], ee1);
          ee0 = fmaf(c4.x, wec[16], ee0); ee1 = fmaf(c4.y, wec[17], ee1);
          ee0 = fmaf(c4.z, wec[18], ee0); ee1 = fmaf(c4.w, wec[19], ee1);
          ee0 = fmaf(c5.x, wec[20], ee0); ee1 = fmaf(c5.y, wec[21], ee1);
          ee0 = fmaf(c5.z, wec[22], ee0); ee1 = fmaf(c5.w, wec[23], ee1);
          ee0 = fmaf(c6.x, wec[24], ee0); ee1 = fmaf(c6.y, wec[25], ee1);
          ee0 = fmaf(c6.z, wec[26], ee0); ee1 = fmaf(c6.w, wec[27], ee1);
          ee0 = fmaf(c7.x, wec[28], ee0); ee1 = fmaf(c7.y, wec[29], ee1);
          ee0 = fmaf(c7.z, wec[30], ee0); ee1 = fmaf(c7.w, wec[31], ee1);
          const float eej = ee0 + ee1;
          float pp = qj * (kc + eej);
          pp += __shfl_xor(pp, 1);
          pp += __shfl_xor(pp, 2);
          pp += __shfl_xor(pp, 4);
          const float wv2 = __expf(pp * 0.3535533905932738f);
          sacc += wv2;
          macc = fmaf(wv2, vc + eej, macc);
          // rotate
          c0 = p0; c1 = p1; c2 = p2; c3 = p3; c4 = p4; c5 = p5; c6 = p6; c7 = p7;
          kc = kn; vc = vn;
        }
      }
      osum[(size_t)n * 64 + lane] = macc;
      if (lane == 0) cnt[n] = (float)(end - beg + 1);
    }
  }
  if ((lane & 7) == 0) atomicAdd(&S[lane >> 3], sacc);
}

// ---------------- epilogue 1: out/(S*cnt) @ Wo + bo, +x, LN1 -> h ----------------
__global__ __launch_bounds__(256) void k_ln1(
    const float* __restrict__ osum, const float* __restrict__ cnt,
    const float* __restrict__ S, const float* __restrict__ x,
    const float* __restrict__ Wo, const float* __restrict__ bo,
    const float* __restrict__ g1, const float* __restrict__ b1,
    float* __restrict__ h) {
  __shared__ float Wl[64 * 64];
  for (int t = threadIdx.x; t < 4096; t += 256) Wl[t] = Wo[t];
  __syncthreads();
  const int n = blockIdx.x * 256 + threadIdx.x;
  if (n >= N_NODES) return;

  float inv[8];
#pragma unroll
  for (int hh = 0; hh < 8; ++hh) inv[hh] = 1.0f / S[hh];
  const float invc = 1.0f / cnt[n];

  float val[64];
  const float4* osr = reinterpret_cast<const float4*>(osum + (size_t)n * 64);
#pragma unroll
  for (int j4 = 0; j4 < 16; ++j4) {
    float4 t = osr[j4];
    val[j4 * 4 + 0] = t.x * inv[(j4 * 4 + 0) >> 3] * invc;
    val[j4 * 4 + 1] = t.y * inv[(j4 * 4 + 1) >> 3] * invc;
    val[j4 * 4 + 2] = t.z * inv[(j4 * 4 + 2) >> 3] * invc;
    val[j4 * 4 + 3] = t.w * inv[(j4 * 4 + 3) >> 3] * invc;
  }

  float4 acc[16];
#pragma unroll
  for (int j4 = 0; j4 < 16; ++j4) acc[j4] = make_float4(0.f, 0.f, 0.f, 0.f);
#pragma unroll 4
  for (int i = 0; i < 64; ++i) {
    const float xi = val[i];
    const float4* wrow = reinterpret_cast<const float4*>(Wl + i * 64);
#pragma unroll
    for (int j4 = 0; j4 < 16; ++j4) {
      float4 wv = wrow[j4];
      acc[j4].x = fmaf(xi, wv.x, acc[j4].x);
      acc[j4].y = fmaf(xi, wv.y, acc[j4].y);
      acc[j4].z = fmaf(xi, wv.z, acc[j4].z);
      acc[j4].w = fmaf(xi, wv.w, acc[j4].w);
    }
  }

  const float4* xr = reinterpret_cast<const float4*>(x + (size_t)n * 64);
  const float4* bo4 = reinterpret_cast<const float4*>(bo);
  float t[64];
  float m = 0.f;
#pragma unroll
  for (int j4 = 0; j4 < 16; ++j4) {
    float4 xv = xr[j4]; float4 bb = bo4[j4];
    t[j4 * 4 + 0] = xv.x + acc[j4].x + bb.x;
    t[j4 * 4 + 1] = xv.y + acc[j4].y + bb.y;
    t[j4 * 4 + 2] = xv.z + acc[j4].z + bb.z;
    t[j4 * 4 + 3] = xv.w + acc[j4].w + bb.w;
    m += t[j4 * 4 + 0] + t[j4 * 4 + 1] + t[j4 * 4 + 2] + t[j4 * 4 + 3];
  }
  m *= (1.0f / 64.0f);
  float var = 0.f;
#pragma unroll
  for (int j = 0; j < 64; ++j) { const float dt = t[j] - m; var = fmaf(dt, dt, var); }
  var *= (1.0f / 64.0f);
  const float r = rsqrtf(var + 1e-5f);
  const float4* g14 = reinterpret_cast<const float4*>(g1);
  const float4* b14 = reinterpret_cast<const float4*>(b1);
  float4* hr = reinterpret_cast<float4*>(h + (size_t)n * 64);
#pragma unroll
  for (int j4 = 0; j4 < 16; ++j4) {
    float4 g = g14[j4]; float4 bb = b14[j4]; float4 o;
    o.x = (t[j4 * 4 + 0] - m) * r * g.x + bb.x;
    o.y = (t[j4 * 4 + 1] - m) * r * g.y + bb.y;
    o.z = (t[j4 * 4 + 2] - m) * r * g.z + bb.z;
    o.w = (t[j4 * 4 + 3] - m) * r * g.w + bb.w;
    hr[j4] = o;
  }
}

// ---------------- FFN stage 1: f1 = gelu(h @ Wf1 + bf1) ----------------
__global__ __launch_bounds__(256) void k_ffn1(
    const float* __restrict__ h, const float* __restrict__ Wf1,
    const float* __restrict__ bf1, float* __restrict__ f1) {
  __shared__ float Wl[64 * 128];
  for (int t = threadIdx.x; t < 8192; t += 256) Wl[t] = Wf1[t];
  __syncthreads();
  const int n = blockIdx.x * 256 + threadIdx.x;
  if (n >= N_NODES) return;

  float4 acc[32];
#pragma unroll
  for (int j4 = 0; j4 < 32; ++j4) acc[j4] = make_float4(0.f, 0.f, 0.f, 0.f);
  const float4* xr = reinterpret_cast<const float4*>(h + (size_t)n * 64);
#pragma unroll 2
  for (int i4 = 0; i4 < 16; ++i4) {
    float4 xv = xr[i4];
#pragma unroll
    for (int s = 0; s < 4; ++s) {
      const float xi = (s == 0) ? xv.x : (s == 1) ? xv.y : (s == 2) ? xv.z : xv.w;
      const float4* wrow = reinterpret_cast<const float4*>(Wl + (i4 * 4 + s) * 128);
#pragma unroll
      for (int j4 = 0; j4 < 32; ++j4) {
        float4 wv = wrow[j4];
        acc[j4].x = fmaf(xi, wv.x, acc[j4].x);
        acc[j4].y = fmaf(xi, wv.y, acc[j4].y);
        acc[j4].z = fmaf(xi, wv.z, acc[j4].z);
        acc[j4].w = fmaf(xi, wv.w, acc[j4].w);
      }
    }
  }
  const float4* b4 = reinterpret_cast<const float4*>(bf1);
  float4* orow = reinterpret_cast<float4*>(f1 + (size_t)n * 128);
#pragma unroll
  for (int j4 = 0; j4 < 32; ++j4) {
    float4 a = acc[j4]; float4 bb = b4[j4];
    a.x += bb.x; a.y += bb.y; a.z += bb.z; a.w += bb.w;
    a.x = 0.5f * a.x * (1.0f + erff(a.x * 0.7071067811865475f));
    a.y = 0.5f * a.y * (1.0f + erff(a.y * 0.7071067811865475f));
    a.z = 0.5f * a.z * (1.0f + erff(a.z * 0.7071067811865475f));
    a.w = 0.5f * a.w * (1.0f + erff(a.w * 0.7071067811865475f));
    orow[j4] = a;
  }
}

// ---------------- FFN stage 2 + residual + LN2 -> d_out ----------------
__global__ __launch_bounds__(256) void k_ffn2(
    const float* __restrict__ f1, const float* __restrict__ h,
    const float* __restrict__ Wf2, const float* __restrict__ bf2,
    const float* __restrict__ g2, const float* __restrict__ b2,
    float* __restrict__ out) {
  __shared__ float Wl[128 * 64];
  for (int t = threadIdx.x; t < 8192; t += 256) Wl[t] = Wf2[t];
  __syncthreads();
  const int n = blockIdx.x * 256 + threadIdx.x;
  if (n >= N_NODES) return;

  float4 acc[16];
#pragma unroll
  for (int j4 = 0; j4 < 16; ++j4) acc[j4] = make_float4(0.f, 0.f, 0.f, 0.f);
  const float4* fr = reinterpret_cast<const float4*>(f1 + (size_t)n * 128);
#pragma unroll 2
  for (int i4 = 0; i4 < 32; ++i4) {
    float4 fv = fr[i4];
#pragma unroll
    for (int s = 0; s < 4; ++s) {
      const float fi = (s == 0) ? fv.x : (s == 1) ? fv.y : (s == 2) ? fv.z : fv.w;
      const float4* wrow = reinterpret_cast<const float4*>(Wl + (i4 * 4 + s) * 64);
#pragma unroll
      for (int j4 = 0; j4 < 16; ++j4) {
        float4 wv = wrow[j4];
        acc[j4].x = fmaf(fi, wv.x, acc[j4].x);
        acc[j4].y = fmaf(fi, wv.y, acc[j4].y);
        acc[j4].z = fmaf(fi, wv.z, acc[j4].z);
        acc[j4].w = fmaf(fi, wv.w, acc[j4].w);
      }
    }
  }

  const float4* hr = reinterpret_cast<const float4*>(h + (size_t)n * 64);
  const float4* b4 = reinterpret_cast<const float4*>(bf2);
  float t[64];
  float m = 0.f;
#pragma unroll
  for (int j4 = 0; j4 < 16; ++j4) {
    float4 hv = hr[j4]; float4 bb = b4[j4];
    t[j4 * 4 + 0] = hv.x + acc[j4].x + bb.x;
    t[j4 * 4 + 1] = hv.y + acc[j4].y + bb.y;
    t[j4 * 4 + 2] = hv.z + acc[j4].z + bb.z;
    t[j4 * 4 + 3] = hv.w + acc[j4].w + bb.w;
    m += t[j4 * 4 + 0] + t[j4 * 4 + 1] + t[j4 * 4 + 2] + t[j4 * 4 + 3];
  }
  m *= (1.0f / 64.0f);
  float var = 0.f;
#pragma unroll
  for (int j = 0; j < 64; ++j) { const float dt = t[j] - m; var = fmaf(dt, dt, var); }
  var *= (1.0f / 64.0f);
  const float r = rsqrtf(var + 1e-5f);
  const float4* g24 = reinterpret_cast<const float4*>(g2);
  const float4* b24 = reinterpret_cast<const float4*>(b2);
  float4* orow = reinterpret_cast<float4*>(out + (size_t)n * 64);
#pragma unroll
  for (int j4 = 0; j4 < 16; ++j4) {
    float4 g = g24[j4]; float4 bb = b24[j4]; float4 o;
    o.x = (t[j4 * 4 + 0] - m) * r * g.x + bb.x;
    o.y = (t[j4 * 4 + 1] - m) * r * g.y + bb.y;
    o.z = (t[j4 * 4 + 2] - m) * r * g.z + bb.z;
    o.w = (t[j4 * 4 + 3] - m) * r * g.w + bb.w;
    orow[j4] = o;
  }
}

extern "C" void kernel_launch(void* const* d_in, const int* in_sizes, int n_in,
                              void* d_out, int out_size, void* d_ws, size_t ws_size,
                              hipStream_t stream) {
  const float* x    = (const float*)d_in[0];
  const int*   ei   = (const int*)d_in[1];
  const int*   esrc = ei;
  const int*   edst = ei + N_EDGES;
  const float* ea   = (const float*)d_in[2];
  const float* Wq   = (const float*)d_in[3];
  const float* bq   = (const float*)d_in[4];
  const float* Wk   = (const float*)d_in[5];
  const float* bk   = (const float*)d_in[6];
  const float* Wv   = (const float*)d_in[7];
  const float* bv   = (const float*)d_in[8];
  const float* We   = (const float*)d_in[9];
  const float* be   = (const float*)d_in[10];
  const float* Wo   = (const float*)d_in[11];
  const float* bo   = (const float*)d_in[12];
  const float* g1   = (const float*)d_in[13];
  const float* b1   = (const float*)d_in[14];
  const float* g2   = (const float*)d_in[15];
  const float* b2   = (const float*)d_in[16];
  const float* Wf1  = (const float*)d_in[17];
  const float* bf1  = (const float*)d_in[18];
  const float* Wf2  = (const float*)d_in[19];
  const float* bf2  = (const float*)d_in[20];

  float* ws   = (float*)d_ws;
  float* q    = ws + Q_OFF;
  float* k    = ws + K_OFF;
  float* v    = ws + V_OFF;
  float* osum = ws + OS_OFF;
  float* cnt  = ws + CNT_OFF;
  float* S    = ws + S_OFF;
  float* h    = ws + H_OFF;
  float* f1   = ws + F1_OFF;
  int*   deg    = (int*)(ws + DEG_OFF);
  int*   rowptr = (int*)(ws + RP_OFF);
  int*   woff   = (int*)(ws + WOFF_OFF);
  int*   bsum   = (int*)(ws + BSUM_OFF);
  int2*  pe     = (int2*)(ws + PE_OFF);
  float* out  = (float*)d_out;

  // zero the histogram and the softmax denominator accumulator
  hipMemsetAsync(deg, 0, (size_t)N_NODES * sizeof(int), stream);
  hipMemsetAsync(S, 0, 16 * sizeof(float), stream);

  const dim3 B(256);
  const int nodeBlocks = (N_NODES + 255) / 256;  // 196
  const int edgeBlocks = (N_EDGES + 255) / 256;  // 3125

  k_qkv<<<dim3(nodeBlocks, 3), B, 0, stream>>>(x, Wq, bq, Wk, bk, Wv, bv, q, k, v);
  k_hist<<<dim3(edgeBlocks), B, 0, stream>>>(edst, deg);
  k_scan_a<<<dim3(nodeBlocks), B, 0, stream>>>(deg, bsum);
  k_scan_b<<<dim3(1), B, 0, stream>>>(bsum, nodeBlocks);
  k_scan_c<<<dim3(nodeBlocks), B, 0, stream>>>(deg, bsum, rowptr, woff);
  k_scatter<<<dim3(edgeBlocks), B, 0, stream>>>(esrc, edst, woff, pe);
  k_gather<<<dim3(2048), B, 0, stream>>>(rowptr, pe, ea, q, k, v, We, be, osum, cnt, S);
  k_ln1<<<dim3(nodeBlocks), B, 0, stream>>>(osum, cnt, S, x, Wo, bo, g1, b1, h);
  k_ffn1<<<dim3(nodeBlocks), B, 0, stream>>>(h, Wf1, bf1, f1);
  k_ffn2<<<dim3(nodeBlocks), B, 0, stream>>>(f1, h, Wf2, bf2, g2, b2, out);
}